// Round 14
// baseline (25.922 us; speedup 1.0000x reference)
//
#include <hip/hip_runtime.h>
#include <hip/hip_bf16.h>

// Guided attention loss, two-kernel. r14 = r13 with grid axes swapped.
//   guided(b,x,y) = 1 - exp(-(y/il - x/ol)^2 / (2*sigma^2)),  sigma=0.4
//   out[b]   = sum(guided*att over valid) / ol
//   out[B+b] = sum((guided*att)^2 over valid) / ol
// Shapes fixed: B=64, T_out=2048, T_in=512.
//
// Round 14 (ONE change vs r13): grid = (batch fastest, chunk). Dispatch
// rounds mix all 64 batches -> per-round duration ~= mean over batches,
// and the drain tail holds only rare ol>2040 chunks (was: last 256 WGs all
// batch 63 -> batch-serial tail). Bodies identical to r13 (22.2us).

#define GA_B     64
#define GA_TOUT  2048
#define GA_TIN   512
#define ROWS_PER_WAVE   8
#define NCHUNK          (GA_TOUT / ROWS_PER_WAVE)    // 256 chunks per batch
// KS = sqrt(3.125 * log2(e)):  2^(-(KS*z)^2) = exp(-z^2 * 3.125)
#define KS 2.1233046f

__global__ __launch_bounds__(64)
void ga_partial_kernel(const float* __restrict__ att,
                       const int* __restrict__ ilens,
                       const int* __restrict__ olens,
                       float2* __restrict__ part) {
    const int b       = blockIdx.x;              // batch (fast axis)
    const int chunk   = blockIdx.y;              // row chunk
    const int waveRow = chunk * ROWS_PER_WAVE;
    const int ol      = olens[b];
    if (waveRow >= ol) return;                   // dead block: k2 won't read it

    const int lane = threadIdx.x;
    const int il   = ilens[b];

    const int q = lane >> 4;                     // row within 4-row group
    const int l = lane & 15;                     // column sub-group
    const int full_w = il >> 6;                  // fully-valid 64-col windows
    const int nw     = (il + 63) >> 6;           // total windows incl. boundary

    const float inv_il_s = KS / (float)il;
    const float inv_ol_s = KS / (float)ol;
    const float* __restrict__ bbase = att + (size_t)b * GA_TOUT * GA_TIN;

    int   row[2];
    float gx[2];
    #pragma unroll
    for (int g = 0; g < 2; ++g) {
        row[g] = waveRow + g * 4 + q;
        gx[g]  = (float)row[g] * inv_ol_s;
    }

    float ysb[4];
    #pragma unroll
    for (int j = 0; j < 4; ++j)
        ysb[j] = (float)((l << 2) + j) * inv_il_s;

    // boundary-window (index full_w) column masks
    float mb[4];
    #pragma unroll
    for (int j = 0; j < 4; ++j) {
        const int col = (full_w << 6) + (l << 2) + j;
        mb[j] = (col < il) ? 1.0f : 0.0f;
    }

    // ---- loads: up to 16 float4 issued before compute ----
    float4 A[2][8];
    #pragma unroll
    for (int w = 0; w < 8; ++w) {
        #pragma unroll
        for (int g = 0; g < 2; ++g) {
            A[g][w] = make_float4(0.f, 0.f, 0.f, 0.f);
            if (w < nw && row[g] < ol) {
                A[g][w] = ((const float4*)(bbase + (size_t)row[g] * GA_TIN))
                          [(w << 4) + l];
            }
        }
    }

    float l1 = 0.0f, l2 = 0.0f;

    // ---- compute: full windows unmasked, boundary window masked ----
    #pragma unroll
    for (int w = 0; w < 8; ++w) {
        if (w < full_w) {                        // wave-uniform: unmasked
            const float off = (float)(w << 6) * inv_il_s;
            #pragma unroll
            for (int g = 0; g < 2; ++g) {
                const float  c = off - gx[g];
                const float4 a = A[g][w];
                #pragma unroll
                for (int j = 0; j < 4; ++j) {
                    const float av = (j == 0) ? a.x : (j == 1) ? a.y
                                   : (j == 2) ? a.z : a.w;
                    const float wv = ysb[j] + c;
                    const float E  = exp2f(-wv * wv);
                    const float e  = av - av * E;
                    l1 += e;
                    l2 += e * e;
                }
            }
        } else if (w < nw) {                     // boundary window: masked
            const float off = (float)(w << 6) * inv_il_s;
            #pragma unroll
            for (int g = 0; g < 2; ++g) {
                const float  c = off - gx[g];
                const float4 a = A[g][w];
                #pragma unroll
                for (int j = 0; j < 4; ++j) {
                    const float av = (j == 0) ? a.x : (j == 1) ? a.y
                                   : (j == 2) ? a.z : a.w;
                    const float wv = ysb[j] + c;
                    const float E  = exp2f(-wv * wv);
                    const float e  = (av - av * E) * mb[j];
                    l1 += e;
                    l2 += e * e;
                }
            }
        }
    }

    // ---- wave reduce (no barrier, no LDS) ----
    #pragma unroll
    for (int o = 32; o > 0; o >>= 1) {
        l1 += __shfl_down(l1, o, 64);
        l2 += __shfl_down(l2, o, 64);
    }
    if (lane == 0)
        part[b * NCHUNK + chunk] = make_float2(l1, l2);
}

__global__ __launch_bounds__(64)
void ga_final_kernel(const float2* __restrict__ part,
                     const int* __restrict__ olens,
                     float* __restrict__ out) {
    const int b  = blockIdx.x;
    const int t  = threadIdx.x;
    const int ol = olens[b];
    const int nchunks = (ol + ROWS_PER_WAVE - 1) >> 3;   // <= 256 live chunks
    float l1 = 0.0f, l2 = 0.0f;
    for (int c = t; c < nchunks; c += 64) {
        const float2 p = part[b * NCHUNK + c];
        l1 += p.x; l2 += p.y;
    }
    #pragma unroll
    for (int o = 32; o > 0; o >>= 1) {
        l1 += __shfl_down(l1, o, 64);
        l2 += __shfl_down(l2, o, 64);
    }
    if (t == 0) {
        const float d = (float)ol;
        out[b]        = l1 / d;
        out[GA_B + b] = l2 / d;
    }
}

extern "C" void kernel_launch(void* const* d_in, const int* in_sizes, int n_in,
                              void* d_out, int out_size, void* d_ws, size_t ws_size,
                              hipStream_t stream) {
    const float* att   = (const float*)d_in[0];
    const int*   ilens = (const int*)d_in[1];
    const int*   olens = (const int*)d_in[2];
    float*       out   = (float*)d_out;
    float2*      part  = (float2*)d_ws;   // 64 * 256 * 8 B = 128 KB

    dim3 grid1(GA_B, NCHUNK);             // batch fastest -> balanced rounds
    ga_partial_kernel<<<grid1, 64, 0, stream>>>(att, ilens, olens, part);
    ga_final_kernel<<<GA_B, 64, 0, stream>>>(part, olens, out);
}

// Round 15
// 22.175 us; speedup vs baseline: 1.1690x; 1.1690x over previous
//
#include <hip/hip_runtime.h>
#include <hip/hip_bf16.h>

// Guided attention loss, two-kernel. r15 = r13 + __launch_bounds__(64,4) on k1.
//   guided(b,x,y) = 1 - exp(-(y/il - x/ol)^2 / (2*sigma^2)),  sigma=0.4
//   out[b]   = sum(guided*att over valid) / ol
//   out[B+b] = sum((guided*att)^2 over valid) / ol
// Shapes fixed: B=64, T_out=2048, T_in=512.
//
// Round 15 (ONE change vs r13): __launch_bounds__(64, 4) raises the VGPR
// budget to ~128 so the compiler can keep all 16 float4 loads in flight
// (r7 counters showed VGPR=52 -> loads batched ~6 at a time -> MLP-starved:
// ~2 TB/s effective vs the 6.3 TB/s cold-HBM floor; replays are cold because
// the harness's 1 GiB d_ws re-poison thrashes L3 between replays).
// r14 lesson: batch-fastest dispatch order costs +3.7us; chunk-fastest kept.

#define GA_B     64
#define GA_TOUT  2048
#define GA_TIN   512
#define ROWS_PER_WAVE   8
#define NCHUNK          (GA_TOUT / ROWS_PER_WAVE)    // 256 chunks per batch
// KS = sqrt(3.125 * log2(e)):  2^(-(KS*z)^2) = exp(-z^2 * 3.125)
#define KS 2.1233046f

__global__ __launch_bounds__(64, 4)
void ga_partial_kernel(const float* __restrict__ att,
                       const int* __restrict__ ilens,
                       const int* __restrict__ olens,
                       float2* __restrict__ part) {
    const int b       = blockIdx.y;
    const int waveRow = blockIdx.x * ROWS_PER_WAVE;
    const int ol      = olens[b];
    if (waveRow >= ol) return;                   // dead block: k2 won't read it

    const int lane = threadIdx.x;
    const int il   = ilens[b];

    const int q = lane >> 4;                     // row within 4-row group
    const int l = lane & 15;                     // column sub-group
    const int full_w = il >> 6;                  // fully-valid 64-col windows
    const int nw     = (il + 63) >> 6;           // total windows incl. boundary

    const float inv_il_s = KS / (float)il;
    const float inv_ol_s = KS / (float)ol;
    const float* __restrict__ bbase = att + (size_t)b * GA_TOUT * GA_TIN;

    int   row[2];
    float gx[2];
    #pragma unroll
    for (int g = 0; g < 2; ++g) {
        row[g] = waveRow + g * 4 + q;
        gx[g]  = (float)row[g] * inv_ol_s;
    }

    float ysb[4];
    #pragma unroll
    for (int j = 0; j < 4; ++j)
        ysb[j] = (float)((l << 2) + j) * inv_il_s;

    // boundary-window (index full_w) column masks
    float mb[4];
    #pragma unroll
    for (int j = 0; j < 4; ++j) {
        const int col = (full_w << 6) + (l << 2) + j;
        mb[j] = (col < il) ? 1.0f : 0.0f;
    }

    // ---- loads: 16 float4 issued before compute (now with VGPR headroom) ----
    float4 A[2][8];
    #pragma unroll
    for (int w = 0; w < 8; ++w) {
        #pragma unroll
        for (int g = 0; g < 2; ++g) {
            A[g][w] = make_float4(0.f, 0.f, 0.f, 0.f);
            if (w < nw && row[g] < ol) {
                A[g][w] = ((const float4*)(bbase + (size_t)row[g] * GA_TIN))
                          [(w << 4) + l];
            }
        }
    }

    float l1 = 0.0f, l2 = 0.0f;

    // ---- compute: full windows unmasked, boundary window masked ----
    #pragma unroll
    for (int w = 0; w < 8; ++w) {
        if (w < full_w) {                        // wave-uniform: unmasked
            const float off = (float)(w << 6) * inv_il_s;
            #pragma unroll
            for (int g = 0; g < 2; ++g) {
                const float  c = off - gx[g];
                const float4 a = A[g][w];
                #pragma unroll
                for (int j = 0; j < 4; ++j) {
                    const float av = (j == 0) ? a.x : (j == 1) ? a.y
                                   : (j == 2) ? a.z : a.w;
                    const float wv = ysb[j] + c;
                    const float E  = exp2f(-wv * wv);
                    const float e  = av - av * E;
                    l1 += e;
                    l2 += e * e;
                }
            }
        } else if (w < nw) {                     // boundary window: masked
            const float off = (float)(w << 6) * inv_il_s;
            #pragma unroll
            for (int g = 0; g < 2; ++g) {
                const float  c = off - gx[g];
                const float4 a = A[g][w];
                #pragma unroll
                for (int j = 0; j < 4; ++j) {
                    const float av = (j == 0) ? a.x : (j == 1) ? a.y
                                   : (j == 2) ? a.z : a.w;
                    const float wv = ysb[j] + c;
                    const float E  = exp2f(-wv * wv);
                    const float e  = (av - av * E) * mb[j];
                    l1 += e;
                    l2 += e * e;
                }
            }
        }
    }

    // ---- wave reduce (no barrier, no LDS) ----
    #pragma unroll
    for (int o = 32; o > 0; o >>= 1) {
        l1 += __shfl_down(l1, o, 64);
        l2 += __shfl_down(l2, o, 64);
    }
    if (lane == 0)
        part[b * NCHUNK + blockIdx.x] = make_float2(l1, l2);
}

__global__ __launch_bounds__(64)
void ga_final_kernel(const float2* __restrict__ part,
                     const int* __restrict__ olens,
                     float* __restrict__ out) {
    const int b  = blockIdx.x;
    const int t  = threadIdx.x;
    const int ol = olens[b];
    const int nchunks = (ol + ROWS_PER_WAVE - 1) >> 3;   // <= 256 live chunks
    float l1 = 0.0f, l2 = 0.0f;
    for (int c = t; c < nchunks; c += 64) {
        const float2 p = part[b * NCHUNK + c];
        l1 += p.x; l2 += p.y;
    }
    #pragma unroll
    for (int o = 32; o > 0; o >>= 1) {
        l1 += __shfl_down(l1, o, 64);
        l2 += __shfl_down(l2, o, 64);
    }
    if (t == 0) {
        const float d = (float)ol;
        out[b]        = l1 / d;
        out[GA_B + b] = l2 / d;
    }
}

extern "C" void kernel_launch(void* const* d_in, const int* in_sizes, int n_in,
                              void* d_out, int out_size, void* d_ws, size_t ws_size,
                              hipStream_t stream) {
    const float* att   = (const float*)d_in[0];
    const int*   ilens = (const int*)d_in[1];
    const int*   olens = (const int*)d_in[2];
    float*       out   = (float*)d_out;
    float2*      part  = (float2*)d_ws;   // 64 * 256 * 8 B = 128 KB

    dim3 grid1(NCHUNK, GA_B);
    ga_partial_kernel<<<grid1, 64, 0, stream>>>(att, ilens, olens, part);
    ga_final_kernel<<<GA_B, 64, 0, stream>>>(part, olens, out);
}